// Round 14
// baseline (504.109 us; speedup 1.0000x reference)
//
// GAT fused pipeline v3.5 — pack_w score-branch fixed (pack_wa: parallel Wa=W1@a1,
// kills serial 512-FMA/thread on 32 waves); gemm1 split 2-way (visibility floor
// 65->34us for residual-kernel hunt). All else frozen from v3.4.
#include <hip/hip_runtime.h>
#include <math.h>

#define N_NODES 50000
#define N_EDGES 800000
#define NFEAT 512
#define NHID 64
#define NHEAD 8
#define NCLASS 40
#define NEG_SLOPE 0.2f

#define N_RT 3125           // 50000/16 row tiles
#define SCAN_NBLK 49        // ceil(50000/1024)
#define RT_BLK 3            // rowtiles per gemm1 block (48 rows, 48KB LDS)
#define GEMM1_GRID 1042     // ceil(3125/3); split into 2x521
#define ATT1_CHUNK 12500    // nodes per att1 dispatch (4 dispatches)

typedef __attribute__((ext_vector_type(8))) short short8;
typedef __attribute__((ext_vector_type(4))) short short4v;
typedef __attribute__((ext_vector_type(4))) float f32x4;

__device__ __forceinline__ float bf2f(short s) {
    return __uint_as_float(((unsigned)(unsigned short)s) << 16);
}
__device__ __forceinline__ short f2bf(float f) {
    unsigned u = __float_as_uint(f);
    unsigned r = (u + 0x7FFFu + ((u >> 16) & 1u)) >> 16;
    return (short)(unsigned short)r;
}
// LDS 16B-slot swizzle: staging writes 32-way -> conflict-free (verified r7:
// SQ_LDS_BANK_CONFLICT 2.8M -> 0); reads stay conflict-free; bijective.
__device__ __forceinline__ int swz(int s) { return s ^ ((s >> 4) & 7); }

// h1 row permutation: slot c' = head*64 + f'; orig feature: forig = ((f'&3)<<4)|(f'>>2).
// Wp1a layout (augmented): ((g*16+ks)*9 + ct)*64*8 shorts; ct=8 holds score
// columns [ss_h(2g), sd_h(2g), ss_h(2g+1), sd_h(2g+1), 0...] from Waf (pack_wa).

// ---------------- CSR build ----------------

__global__ void count_deg(const int* __restrict__ el, int* __restrict__ deg) {
    int e = blockIdx.x * blockDim.x + threadIdx.x;
    if (e < N_EDGES) atomicAdd(&deg[el[N_EDGES + e]], 1);
}

__global__ __launch_bounds__(256) void scan1(const int* __restrict__ deg,
                                             int* __restrict__ loc,
                                             int* __restrict__ bsum) {
    int tid = threadIdx.x, lane = tid & 63, w = tid >> 6;
    int base = blockIdx.x * 1024 + tid * 4;
    int d0 = (base + 0 < N_NODES) ? deg[base + 0] : 0;
    int d1 = (base + 1 < N_NODES) ? deg[base + 1] : 0;
    int d2 = (base + 2 < N_NODES) ? deg[base + 2] : 0;
    int d3 = (base + 3 < N_NODES) ? deg[base + 3] : 0;
    int s0 = d0, s1 = s0 + d1, s2 = s1 + d2, s3 = s2 + d3;
    int t = s3;
#pragma unroll
    for (int d = 1; d < 64; d <<= 1) {
        int u = __shfl_up(t, d);
        if (lane >= d) t += u;
    }
    __shared__ int wsum[4];
    if (lane == 63) wsum[w] = t;
    __syncthreads();
    int woff = 0;
#pragma unroll
    for (int j = 0; j < 4; ++j) woff += (j < w) ? wsum[j] : 0;
    int excl = woff + t - s3;
    if (base + 0 < N_NODES) loc[base + 0] = excl + s0;
    if (base + 1 < N_NODES) loc[base + 1] = excl + s1;
    if (base + 2 < N_NODES) loc[base + 2] = excl + s2;
    if (base + 3 < N_NODES) loc[base + 3] = excl + s3;
    if (tid == 255) bsum[blockIdx.x] = woff + t;
}

// scan3 with scan2 folded in: each block reduces bsum[0..bid) itself
__global__ __launch_bounds__(256) void scan3(const int* __restrict__ deg,
                                             const int* __restrict__ loc,
                                             const int* __restrict__ bsum,
                                             int* __restrict__ ptr,
                                             int* __restrict__ cursor) {
    __shared__ int sOff;
    if (threadIdx.x < 64) {
        int lane = threadIdx.x;
        int v = (lane < SCAN_NBLK && lane < (int)blockIdx.x) ? bsum[lane] : 0;
#pragma unroll
        for (int m = 1; m < 64; m <<= 1) v += __shfl_xor(v, m);
        if (lane == 0) sOff = v;
    }
    __syncthreads();
    int off = sOff;
    int base = blockIdx.x * 1024 + threadIdx.x * 4;
    if (blockIdx.x == 0 && threadIdx.x == 0) ptr[0] = 0;
#pragma unroll
    for (int k = 0; k < 4; ++k) {
        int i = base + k;
        if (i < N_NODES) {
            int P = off + loc[i];
            ptr[i + 1] = P;
            cursor[i] = P - deg[i];
        }
    }
}

__global__ void scatter_k(const int* __restrict__ el, int* __restrict__ cursor,
                          int* __restrict__ esrc) {
    int e = blockIdx.x * blockDim.x + threadIdx.x;
    if (e >= N_EDGES) return;
    int dst = el[N_EDGES + e];
    int p = atomicAdd(&cursor[dst], 1);
    esrc[p] = el[e];
}

// ---------------- pack_wa: Waf[(head*2+s)*512 + k] = sum_f W1[head][k][f]*a1[head][s*64+f] ----
// 8192 dot-products of length 64; 16 lanes per output (lane r sums 4 floats, xor-reduce).
__global__ __launch_bounds__(256) void pack_wa(const float* __restrict__ W1,
                                               const float* __restrict__ a1,
                                               float* __restrict__ Waf) {
    int q = blockIdx.x * 16 + (threadIdx.x >> 4);   // output id, [0, 8192)
    int r = threadIdx.x & 15;
    int k = q & 511;
    int hs = q >> 9;                                // head*2+s
    int head = hs >> 1, s = hs & 1;
    f32x4 wv = *(const f32x4*)(W1 + (size_t)head * NFEAT * NHID + (size_t)k * NHID + r * 4);
    f32x4 av = *(const f32x4*)(a1 + head * 128 + s * 64 + r * 4);
    float sum = wv[0] * av[0] + wv[1] * av[1] + wv[2] * av[2] + wv[3] * av[3];
#pragma unroll
    for (int m = 1; m < 16; m <<= 1) sum += __shfl_xor(sum, m);
    if (r == 0) Waf[q] = sum;
}

// ---------------- pack W1(+scores), W2 into MFMA B-fragment layout (bf16) ----------------
__global__ __launch_bounds__(256) void pack_w(const float* __restrict__ W1,
                                              const float* __restrict__ W2,
                                              const float* __restrict__ Waf,
                                              short* __restrict__ Wp1a,
                                              short* __restrict__ Wp2) {
    int t = blockIdx.x * 256 + threadIdx.x;
    if (t < 36864) {                    // 4g x 16ks x 9ct x 64l
        int l = t & 63;
        int idx = t >> 6;               // 0..575
        int ct = idx % 9;
        int ksg = idx / 9;              // g*16+ks
        int ks = ksg & 15, g = ksg >> 4;
        short8 o;
        if (ct < 8) {
            int c = g * 128 + ct * 16 + (l & 15);
            int head = c >> 6, f = c & 63;
            int k0 = ks * 32 + (l >> 4) * 8;
#pragma unroll
            for (int j = 0; j < 8; ++j)
                o[j] = f2bf(W1[(size_t)head * NFEAT * NHID + (k0 + j) * NHID + f]);
        } else {
            // score columns: col 0..3 = [ss(2g), sd(2g), ss(2g+1), sd(2g+1)] from Waf
            int col = l & 15;
            int k0 = ks * 32 + (l >> 4) * 8;
#pragma unroll
            for (int j = 0; j < 8; ++j) o[j] = 0;
            if (col < 4) {
                int head = 2 * g + (col >> 1);
                int s = col & 1;
                const float* wp = Waf + (head * 2 + s) * 512 + k0;
#pragma unroll
                for (int j = 0; j < 8; ++j) o[j] = f2bf(wp[j]);
            }
        }
        *(short8*)(Wp1a + (size_t)t * 8) = o;
    } else if (t < 36864 + 3072) {
        int u = t - 36864;
        int l = u & 63;
        int kc = u >> 6;                 // ks*3+ct
        int ct2 = kc % 3, ks = kc / 3;
        int col = ct2 * 16 + (l & 15);
        short8 o;
#pragma unroll
        for (int j = 0; j < 8; ++j) {
            int kp = ks * 32 + (l >> 4) * 8 + j;      // permuted K slot (= c')
            int head = kp >> 6, fp = kp & 63;
            int l15 = fp >> 2, ctp = fp & 3;
            int ct = ((head & 1) << 2) | ctp;
            int gg = head >> 1;
            int orig_k = gg * 128 + ct * 16 + l15;
            o[j] = (col < NCLASS) ? f2bf(W2[(size_t)orig_k * NCLASS + col]) : (short)0;
        }
        *(short8*)(Wp2 + (size_t)u * 8) = o;
    }
}

// ---------------- gemm1 v3.5: 3 rowtiles/block, 2 row-range dispatches ----
__global__ __launch_bounds__(256, 3) void gemm1(const float* __restrict__ x,
                                                const short* __restrict__ Wp1a,
                                                short* __restrict__ h1p,
                                                float* __restrict__ s1s,
                                                float* __restrict__ s1d,
                                                int blk0) {
    __shared__ short As[RT_BLK * 16 * 64 * 8];     // 48 KB
    int w = threadIdx.x >> 6, l = threadIdx.x & 63;
    int g = w;                                 // wave = colgroup
    int rt0 = (blk0 + blockIdx.x) * RT_BLK;
    int row0 = rt0 * 16;

    // stage 48 rows x 512 cols of x into LDS A-frag layout (swizzled slots)
#pragma unroll
    for (int u = 0; u < 4 * RT_BLK; ++u) {
        int idx = threadIdx.x + u * 256;       // 0..3071
        int rl = idx >> 6, cg = idx & 63;      // row-local (0..47), col-group
        int row = row0 + rl;
        short8 o;
        if (row < N_NODES) {
            const float* p = x + (size_t)row * NFEAT + cg * 8;
            f32x4 v0 = __builtin_nontemporal_load((const f32x4*)p);
            f32x4 v1 = __builtin_nontemporal_load((const f32x4*)(p + 4));
            o[0] = f2bf(v0[0]); o[1] = f2bf(v0[1]); o[2] = f2bf(v0[2]); o[3] = f2bf(v0[3]);
            o[4] = f2bf(v1[0]); o[5] = f2bf(v1[1]); o[6] = f2bf(v1[2]); o[7] = f2bf(v1[3]);
        } else {
#pragma unroll
            for (int j = 0; j < 8; ++j) o[j] = 0;
        }
        int rtl = rl >> 4, rloc = rl & 15, ks = cg >> 2, sub = cg & 3;
        int slot = (rtl * 16 + ks) * 64 + rloc + sub * 16;
        *(short8*)(As + swz(slot) * 8) = o;
    }
    __syncthreads();

    f32x4 acc[RT_BLK][9];
#pragma unroll
    for (int i = 0; i < RT_BLK; ++i)
#pragma unroll
        for (int ct = 0; ct < 9; ++ct) acc[i][ct] = (f32x4){0.f, 0.f, 0.f, 0.f};

    const short* bP = Wp1a + (size_t)g * (16 * 9 * 512) + l * 8;   // ks stride 4608
#pragma unroll 2
    for (int ks = 0; ks < 16; ++ks) {
        short8 b[9];
#pragma unroll
        for (int ct = 0; ct < 9; ++ct) b[ct] = *(const short8*)(bP + ks * 4608 + ct * 512);
        short8 a[RT_BLK];
#pragma unroll
        for (int i = 0; i < RT_BLK; ++i)
            a[i] = *(const short8*)(As + swz((i * 16 + ks) * 64 + l) * 8);
#pragma unroll
        for (int i = 0; i < RT_BLK; ++i)
#pragma unroll
            for (int ct = 0; ct < 9; ++ct)
                acc[i][ct] = __builtin_amdgcn_mfma_f32_16x16x32_bf16(a[i], b[ct], acc[i][ct], 0, 0, 0);
    }

    int l15 = l & 15;
    int rbase = (l >> 4) * 4;
#pragma unroll
    for (int i = 0; i < RT_BLK; ++i)
#pragma unroll
        for (int r = 0; r < 4; ++r) {
            int row = (rt0 + i) * 16 + rbase + r;
            if (row < N_NODES) {
                short4v o0, o1;
#pragma unroll
                for (int c = 0; c < 4; ++c) { o0[c] = f2bf(acc[i][c][r]); o1[c] = f2bf(acc[i][4 + c][r]); }
                size_t base = (size_t)row * 512 + g * 128 + l15 * 4;
                *(short4v*)(h1p + base) = o0;
                *(short4v*)(h1p + base + 64) = o1;
                float sv = acc[i][8][r];
                if (l15 == 0)      s1s[row * 8 + 2 * g]     = sv;
                else if (l15 == 1) s1d[row * 8 + 2 * g]     = sv;
                else if (l15 == 2) s1s[row * 8 + 2 * g + 1] = sv;
                else if (l15 == 3) s1d[row * 8 + 2 * g + 1] = sv;
            }
        }
}

// ---------------- fused layer-1 attention: wave per dst, ALL heads ----------------
// Node-range chunked (4 dispatches) for profiler visibility; pipelined 4-wide gather.
__global__ __launch_bounds__(256, 4) void att1(const int* __restrict__ ptr,
                                               const int* __restrict__ esrc,
                                               const float* __restrict__ s1s,
                                               const float* __restrict__ s1d,
                                               const short* __restrict__ h1p,
                                               const float* __restrict__ b1,
                                               short* __restrict__ hcat,
                                               int n0) {
    int n = n0 + blockIdx.x * 4 + (threadIdx.x >> 6);
    int l = threadIdx.x & 63;
    if (n >= N_NODES) return;
    int beg = ptr[n], end = ptr[n + 1];
    int h = l >> 3;
    float sd = s1d[n * 8 + h];
    float den = 0.f;
    float acc[8] = {0.f, 0.f, 0.f, 0.f, 0.f, 0.f, 0.f, 0.f};
    const short* hb = h1p + l * 8;
    if (beg < end) {
        int last = end - 1;
        int p1 = (beg + 1 <= last) ? beg + 1 : last;
        int p2 = (beg + 2 <= last) ? beg + 2 : last;
        int p3 = (beg + 3 <= last) ? beg + 3 : last;
        int s0 = esrc[beg], s1 = esrc[p1], s2 = esrc[p2], s3 = esrc[p3];
        short8 v0 = *(const short8*)(hb + (size_t)s0 * 512);
        short8 v1 = *(const short8*)(hb + (size_t)s1 * 512);
        short8 v2 = *(const short8*)(hb + (size_t)s2 * 512);
        short8 v3 = *(const short8*)(hb + (size_t)s3 * 512);
        float ss0 = s1s[s0 * 8 + h], ss1 = s1s[s1 * 8 + h];
        float ss2 = s1s[s2 * 8 + h], ss3 = s1s[s3 * 8 + h];
        for (int i = beg; i < end; i += 4) {
            int ni = i + 4;
            int t0 = s0, t1 = s1, t2 = s2, t3 = s3;
            short8 u0 = v0, u1 = v1, u2 = v2, u3 = v3;
            float ts0 = ss0, ts1 = ss1, ts2 = ss2, ts3 = ss3;
            if (ni < end) {                       // wave-uniform branch
                int q1 = (ni + 1 <= last) ? ni + 1 : last;
                int q2 = (ni + 2 <= last) ? ni + 2 : last;
                int q3 = (ni + 3 <= last) ? ni + 3 : last;
                t0 = esrc[ni]; t1 = esrc[q1]; t2 = esrc[q2]; t3 = esrc[q3];
                u0 = *(const short8*)(hb + (size_t)t0 * 512);
                u1 = *(const short8*)(hb + (size_t)t1 * 512);
                u2 = *(const short8*)(hb + (size_t)t2 * 512);
                u3 = *(const short8*)(hb + (size_t)t3 * 512);
                ts0 = s1s[t0 * 8 + h]; ts1 = s1s[t1 * 8 + h];
                ts2 = s1s[t2 * 8 + h]; ts3 = s1s[t3 * 8 + h];
            }
            float e0 = ss0 + sd, e1 = ss1 + sd, e2 = ss2 + sd, e3 = ss3 + sd;
            e0 = fmaxf(e0, NEG_SLOPE * e0);
            e1 = fmaxf(e1, NEG_SLOPE * e1);
            e2 = fmaxf(e2, NEG_SLOPE * e2);
            e3 = fmaxf(e3, NEG_SLOPE * e3);
            float w0 = __expf(e0);
            float w1 = (i + 1 < end) ? __expf(e1) : 0.f;
            float w2 = (i + 2 < end) ? __expf(e2) : 0.f;
            float w3 = (i + 3 < end) ? __expf(e3) : 0.f;
            den += (w0 + w1) + (w2 + w3);
#pragma unroll
            for (int j = 0; j < 8; ++j)
                acc[j] += (w0 * bf2f(v0[j]) + w1 * bf2f(v1[j])) +
                          (w2 * bf2f(v2[j]) + w3 * bf2f(v3[j]));
            s0 = t0; s1 = t1; s2 = t2; s3 = t3;
            v0 = u0; v1 = u1; v2 = u2; v3 = u3;
            ss0 = ts0; ss1 = ts1; ss2 = ts2; ss3 = ts3;
        }
    }
    float rden = 1.f / fmaxf(den, 1e-16f);
    short8 o;
#pragma unroll
    for (int j = 0; j < 8; ++j) {
        // permuted slot c' = l*8+j  ->  orig b1 index = head*64 + (j&3)*16 + (l&7)*2 + (j>>2)
        int forig = (j & 3) * 16 + (l & 7) * 2 + (j >> 2);
        float v = acc[j] * rden + b1[h * 64 + forig];
        v = v > 0.f ? v : (__expf(v) - 1.f);    // ELU
        o[j] = f2bf(v);
    }
    *(short8*)(hcat + (size_t)n * 512 + l * 8) = o;
}

// ---------------- gemm2: row-major hcat A-frags + fused s2 scores; h2 PADDED to 64 cols ----
__global__ __launch_bounds__(256) void gemm2(const short* __restrict__ hcat,
                                             const short* __restrict__ Wp2,
                                             const float* __restrict__ a2,
                                             short* __restrict__ h2p,
                                             float* __restrict__ s2s,
                                             float* __restrict__ s2d) {
    int w = threadIdx.x >> 6, l = threadIdx.x & 63;
    int rt = blockIdx.x * 4 + w;                  // < 3128
    int arow = rt * 16 + (l & 15);
    const short* aBase = hcat + (size_t)arow * 512 + (l >> 4) * 8;
    f32x4 acc[3];
#pragma unroll
    for (int ct = 0; ct < 3; ++ct) acc[ct] = (f32x4){0.f, 0.f, 0.f, 0.f};
#pragma unroll 2
    for (int ks = 0; ks < 16; ++ks) {
        short8 a = *(const short8*)(aBase + ks * 32);
        const short* bp = Wp2 + (size_t)(ks * 3) * 512 + l * 8;
#pragma unroll
        for (int ct = 0; ct < 3; ++ct) {
            short8 b = *(const short8*)(bp + ct * 512);
            acc[ct] = __builtin_amdgcn_mfma_f32_16x16x32_bf16(a, b, acc[ct], 0, 0, 0);
        }
    }
    float ps[4] = {0.f, 0.f, 0.f, 0.f}, pd[4] = {0.f, 0.f, 0.f, 0.f};
    int cl = l & 15, rb = (l >> 4) * 4;
#pragma unroll
    for (int ct = 0; ct < 3; ++ct) {
        int col = ct * 16 + cl;
#pragma unroll
        for (int r = 0; r < 4; ++r) {
            int row = rt * 16 + rb + r;
            if (row < N_NODES) h2p[(size_t)row * 64 + col] = f2bf(acc[ct][r]);
        }
        if (col < NCLASS) {
#pragma unroll
            for (int r = 0; r < 4; ++r) {
                ps[r] += acc[ct][r] * a2[col];
                pd[r] += acc[ct][r] * a2[NCLASS + col];
            }
        }
    }
#pragma unroll
    for (int mask = 1; mask < 16; mask <<= 1)
#pragma unroll
        for (int r = 0; r < 4; ++r) {
            ps[r] += __shfl_xor(ps[r], mask);
            pd[r] += __shfl_xor(pd[r], mask);
        }
    if (cl == 0) {
#pragma unroll
        for (int r = 0; r < 4; ++r) {
            int row = rt * 16 + rb + r;
            if (row < N_NODES) { s2s[row] = ps[r]; s2d[row] = pd[r]; }
        }
    }
}

// ---------------- fused layer-2 attention + log_softmax: 4 edge-groups x 16 lanes ----
__global__ __launch_bounds__(256, 4) void att2(const int* __restrict__ ptr,
                                               const int* __restrict__ esrc,
                                               const float* __restrict__ s2s,
                                               const float* __restrict__ s2d,
                                               const short* __restrict__ h2p,
                                               const float* __restrict__ b2,
                                               float* __restrict__ out) {
    int n = blockIdx.x * 4 + (threadIdx.x >> 6);
    int l = threadIdx.x & 63;
    if (n >= N_NODES) return;
    int beg = ptr[n], end = ptr[n + 1];
    float sd = s2d[n];
    int grp = l >> 4, cl = l & 15;
    bool act16 = cl < 10;                 // classes cl*4..cl*4+3 valid iff cl<10
    float den = 0.f, a0 = 0.f, a1 = 0.f, a2v = 0.f, a3 = 0.f;
    if (beg < end) {
        int last = end - 1;
        for (int i = beg; i < end; i += 4) {
            int e = i + grp;
            bool valid = e < end;
            int src = esrc[valid ? e : last];
            float sc = s2s[src] + sd;
            sc = fmaxf(sc, NEG_SLOPE * sc);
            float wgt = valid ? __expf(sc) : 0.f;
            short4v hv = *(const short4v*)(h2p + (size_t)src * 64 + cl * 4);
            den += wgt;
            if (act16) {
                a0 += wgt * bf2f(hv[0]);
                a1 += wgt * bf2f(hv[1]);
                a2v += wgt * bf2f(hv[2]);
                a3 += wgt * bf2f(hv[3]);
            }
        }
    }
    // sum the 4 edge-groups (lanes with equal cl): xor 16, 32
#pragma unroll
    for (int m = 16; m < 64; m <<= 1) {
        den += __shfl_xor(den, m);
        a0  += __shfl_xor(a0, m);
        a1  += __shfl_xor(a1, m);
        a2v += __shfl_xor(a2v, m);
        a3  += __shfl_xor(a3, m);
    }
    float rden = 1.f / fmaxf(den, 1e-16f);
    float v0, v1, v2, v3;
    if (act16) {
        int c0 = cl * 4;
        v0 = a0 * rden + b2[c0 + 0];
        v1 = a1 * rden + b2[c0 + 1];
        v2 = a2v * rden + b2[c0 + 2];
        v3 = a3 * rden + b2[c0 + 3];
    } else { v0 = v1 = v2 = v3 = -INFINITY; }
    // log_softmax over 40 classes: reduce within each 16-lane quarter (quarters identical)
    float mx = fmaxf(fmaxf(v0, v1), fmaxf(v2, v3));
#pragma unroll
    for (int m = 1; m < 16; m <<= 1) mx = fmaxf(mx, __shfl_xor(mx, m));
    float e0 = act16 ? __expf(v0 - mx) : 0.f;
    float e1 = act16 ? __expf(v1 - mx) : 0.f;
    float e2 = act16 ? __expf(v2 - mx) : 0.f;
    float e3 = act16 ? __expf(v3 - mx) : 0.f;
    float s = (e0 + e1) + (e2 + e3);
#pragma unroll
    for (int m = 1; m < 16; m <<= 1) s += __shfl_xor(s, m);
    float ls = __logf(s);
    if (l < 16 && act16) {
        int c0 = cl * 4;
        out[(size_t)n * NCLASS + c0 + 0] = v0 - mx - ls;
        out[(size_t)n * NCLASS + c0 + 1] = v1 - mx - ls;
        out[(size_t)n * NCLASS + c0 + 2] = v2 - mx - ls;
        out[(size_t)n * NCLASS + c0 + 3] = v3 - mx - ls;
    }
}

// ---------------- launch ----------------

extern "C" void kernel_launch(void* const* d_in, const int* in_sizes, int n_in,
                              void* d_out, int out_size, void* d_ws, size_t ws_size,
                              hipStream_t stream) {
    const float* x  = (const float*)d_in[0];
    const int*   el = (const int*)d_in[1];
    const float* W1 = (const float*)d_in[2];
    const float* a1 = (const float*)d_in[3];
    const float* b1 = (const float*)d_in[4];
    const float* W2 = (const float*)d_in[5];
    const float* a2 = (const float*)d_in[6];
    const float* b2 = (const float*)d_in[7];
    float* out = (float*)d_out;

    short* sbase = (short*)d_ws;
    short* Wp1a  = sbase;                          //    294,912
    short* h2p   = sbase + 4000000;                //  3,200,000 (padded h2: 50000 x 64)
    short* hcat  = sbase + 25624576;               // 25,624,576 (row-major, permuted cols)
    short* h1p   = sbase + 51249152;               // 25,600,000
    short* Wp2   = sbase + 77111296;               //     24,576
    float* fbase = (float*)(sbase + 79135872);
    float* s1s   = fbase;                          //    400,000
    float* s1d   = fbase + 400000;                 //    400,000
    float* s2s   = fbase + 800000;                 //     50,000
    float* s2d   = fbase + 850000;                 //     50,000
    int*   ibase = (int*)(fbase + 900000);
    int*   deg    = ibase;                         //     50,000
    int*   ptr    = ibase + 50000;                 //     50,001
    int*   cursor = ibase + 100001;                //     50,000
    int*   esrc   = ibase + 150001;                //    800,000
    int*   loc    = ibase + 950001;                //     50,000
    int*   bsum   = ibase + 1000001;               //         64
    float* Waf    = (float*)(ibase + 1000128);     //      8,192 (Wa = W1@a1, fp32)

    // ---- CSR build ----
    hipMemsetAsync(deg, 0, (size_t)N_NODES * 4, stream);
    count_deg<<<(N_EDGES + 255) / 256, 256, 0, stream>>>(el, deg);
    scan1<<<SCAN_NBLK, 256, 0, stream>>>(deg, loc, bsum);
    scan3<<<SCAN_NBLK, 256, 0, stream>>>(deg, loc, bsum, ptr, cursor);
    scatter_k<<<(N_EDGES + 255) / 256, 256, 0, stream>>>(el, cursor, esrc);

    // ---- weight packing (Wa parallel, then fragment pack) ----
    pack_wa<<<512, 256, 0, stream>>>(W1, a1, Waf);
    pack_w<<<156, 256, 0, stream>>>(W1, W2, Waf, Wp1a, Wp2);

    // ---- layer 1 ----
    gemm1<<<521, 256, 0, stream>>>(x, Wp1a, h1p, s1s, s1d, 0);
    gemm1<<<521, 256, 0, stream>>>(x, Wp1a, h1p, s1s, s1d, 521);
    att1<<<ATT1_CHUNK / 4, 256, 0, stream>>>(ptr, esrc, s1s, s1d, h1p, b1, hcat, 0);
    att1<<<ATT1_CHUNK / 4, 256, 0, stream>>>(ptr, esrc, s1s, s1d, h1p, b1, hcat, 12500);
    att1<<<ATT1_CHUNK / 4, 256, 0, stream>>>(ptr, esrc, s1s, s1d, h1p, b1, hcat, 25000);
    att1<<<ATT1_CHUNK / 4, 256, 0, stream>>>(ptr, esrc, s1s, s1d, h1p, b1, hcat, 37500);

    // ---- layer 2 ----
    gemm2<<<782, 256, 0, stream>>>(hcat, Wp2, a2, h2p, s2s, s2d);
    att2<<<(N_NODES + 3) / 4, 256, 0, stream>>>(ptr, esrc, s2s, s2d, h2p, b2, out);
}

// Round 15
// 471.712 us; speedup vs baseline: 1.0687x; 1.0687x over previous
//
// GAT fused pipeline v3.6 — diagnostics complete: att1 + gemm1 merged back to
// single dispatches (reclaims ~22us split tax). All optimizations retained:
// pack_wa parallel scores, gemm1 9-col scores-in-GEMM (RT_BLK=3, swizzled LDS),
// att1 full-row gather, att2 4x16 edge-group layout w/ padded h2.
#include <hip/hip_runtime.h>
#include <math.h>

#define N_NODES 50000
#define N_EDGES 800000
#define NFEAT 512
#define NHID 64
#define NHEAD 8
#define NCLASS 40
#define NEG_SLOPE 0.2f

#define N_RT 3125           // 50000/16 row tiles
#define SCAN_NBLK 49        // ceil(50000/1024)
#define RT_BLK 3            // rowtiles per gemm1 block (48 rows, 48KB LDS)
#define GEMM1_GRID 1042     // ceil(3125/3)

typedef __attribute__((ext_vector_type(8))) short short8;
typedef __attribute__((ext_vector_type(4))) short short4v;
typedef __attribute__((ext_vector_type(4))) float f32x4;

__device__ __forceinline__ float bf2f(short s) {
    return __uint_as_float(((unsigned)(unsigned short)s) << 16);
}
__device__ __forceinline__ short f2bf(float f) {
    unsigned u = __float_as_uint(f);
    unsigned r = (u + 0x7FFFu + ((u >> 16) & 1u)) >> 16;
    return (short)(unsigned short)r;
}
// LDS 16B-slot swizzle: staging writes 32-way -> conflict-free (verified r7:
// SQ_LDS_BANK_CONFLICT 2.8M -> 0); reads stay conflict-free; bijective.
__device__ __forceinline__ int swz(int s) { return s ^ ((s >> 4) & 7); }

// h1 row permutation: slot c' = head*64 + f'; orig feature: forig = ((f'&3)<<4)|(f'>>2).
// Wp1a layout (augmented): ((g*16+ks)*9 + ct)*64*8 shorts; ct=8 holds score
// columns [ss_h(2g), sd_h(2g), ss_h(2g+1), sd_h(2g+1), 0...] from Waf (pack_wa).

// ---------------- CSR build ----------------

__global__ void count_deg(const int* __restrict__ el, int* __restrict__ deg) {
    int e = blockIdx.x * blockDim.x + threadIdx.x;
    if (e < N_EDGES) atomicAdd(&deg[el[N_EDGES + e]], 1);
}

__global__ __launch_bounds__(256) void scan1(const int* __restrict__ deg,
                                             int* __restrict__ loc,
                                             int* __restrict__ bsum) {
    int tid = threadIdx.x, lane = tid & 63, w = tid >> 6;
    int base = blockIdx.x * 1024 + tid * 4;
    int d0 = (base + 0 < N_NODES) ? deg[base + 0] : 0;
    int d1 = (base + 1 < N_NODES) ? deg[base + 1] : 0;
    int d2 = (base + 2 < N_NODES) ? deg[base + 2] : 0;
    int d3 = (base + 3 < N_NODES) ? deg[base + 3] : 0;
    int s0 = d0, s1 = s0 + d1, s2 = s1 + d2, s3 = s2 + d3;
    int t = s3;
#pragma unroll
    for (int d = 1; d < 64; d <<= 1) {
        int u = __shfl_up(t, d);
        if (lane >= d) t += u;
    }
    __shared__ int wsum[4];
    if (lane == 63) wsum[w] = t;
    __syncthreads();
    int woff = 0;
#pragma unroll
    for (int j = 0; j < 4; ++j) woff += (j < w) ? wsum[j] : 0;
    int excl = woff + t - s3;
    if (base + 0 < N_NODES) loc[base + 0] = excl + s0;
    if (base + 1 < N_NODES) loc[base + 1] = excl + s1;
    if (base + 2 < N_NODES) loc[base + 2] = excl + s2;
    if (base + 3 < N_NODES) loc[base + 3] = excl + s3;
    if (tid == 255) bsum[blockIdx.x] = woff + t;
}

// scan3 with scan2 folded in: each block reduces bsum[0..bid) itself
__global__ __launch_bounds__(256) void scan3(const int* __restrict__ deg,
                                             const int* __restrict__ loc,
                                             const int* __restrict__ bsum,
                                             int* __restrict__ ptr,
                                             int* __restrict__ cursor) {
    __shared__ int sOff;
    if (threadIdx.x < 64) {
        int lane = threadIdx.x;
        int v = (lane < SCAN_NBLK && lane < (int)blockIdx.x) ? bsum[lane] : 0;
#pragma unroll
        for (int m = 1; m < 64; m <<= 1) v += __shfl_xor(v, m);
        if (lane == 0) sOff = v;
    }
    __syncthreads();
    int off = sOff;
    int base = blockIdx.x * 1024 + threadIdx.x * 4;
    if (blockIdx.x == 0 && threadIdx.x == 0) ptr[0] = 0;
#pragma unroll
    for (int k = 0; k < 4; ++k) {
        int i = base + k;
        if (i < N_NODES) {
            int P = off + loc[i];
            ptr[i + 1] = P;
            cursor[i] = P - deg[i];
        }
    }
}

__global__ void scatter_k(const int* __restrict__ el, int* __restrict__ cursor,
                          int* __restrict__ esrc) {
    int e = blockIdx.x * blockDim.x + threadIdx.x;
    if (e >= N_EDGES) return;
    int dst = el[N_EDGES + e];
    int p = atomicAdd(&cursor[dst], 1);
    esrc[p] = el[e];
}

// ---------------- pack_wa: Waf[(head*2+s)*512 + k] = sum_f W1[head][k][f]*a1[head][s*64+f] ----
__global__ __launch_bounds__(256) void pack_wa(const float* __restrict__ W1,
                                               const float* __restrict__ a1,
                                               float* __restrict__ Waf) {
    int q = blockIdx.x * 16 + (threadIdx.x >> 4);   // output id, [0, 8192)
    int r = threadIdx.x & 15;
    int k = q & 511;
    int hs = q >> 9;                                // head*2+s
    int head = hs >> 1, s = hs & 1;
    f32x4 wv = *(const f32x4*)(W1 + (size_t)head * NFEAT * NHID + (size_t)k * NHID + r * 4);
    f32x4 av = *(const f32x4*)(a1 + head * 128 + s * 64 + r * 4);
    float sum = wv[0] * av[0] + wv[1] * av[1] + wv[2] * av[2] + wv[3] * av[3];
#pragma unroll
    for (int m = 1; m < 16; m <<= 1) sum += __shfl_xor(sum, m);
    if (r == 0) Waf[q] = sum;
}

// ---------------- pack W1(+scores), W2 into MFMA B-fragment layout (bf16) ----------------
__global__ __launch_bounds__(256) void pack_w(const float* __restrict__ W1,
                                              const float* __restrict__ W2,
                                              const float* __restrict__ Waf,
                                              short* __restrict__ Wp1a,
                                              short* __restrict__ Wp2) {
    int t = blockIdx.x * 256 + threadIdx.x;
    if (t < 36864) {                    // 4g x 16ks x 9ct x 64l
        int l = t & 63;
        int idx = t >> 6;               // 0..575
        int ct = idx % 9;
        int ksg = idx / 9;              // g*16+ks
        int ks = ksg & 15, g = ksg >> 4;
        short8 o;
        if (ct < 8) {
            int c = g * 128 + ct * 16 + (l & 15);
            int head = c >> 6, f = c & 63;
            int k0 = ks * 32 + (l >> 4) * 8;
#pragma unroll
            for (int j = 0; j < 8; ++j)
                o[j] = f2bf(W1[(size_t)head * NFEAT * NHID + (k0 + j) * NHID + f]);
        } else {
            // score columns: col 0..3 = [ss(2g), sd(2g), ss(2g+1), sd(2g+1)] from Waf
            int col = l & 15;
            int k0 = ks * 32 + (l >> 4) * 8;
#pragma unroll
            for (int j = 0; j < 8; ++j) o[j] = 0;
            if (col < 4) {
                int head = 2 * g + (col >> 1);
                int s = col & 1;
                const float* wp = Waf + (head * 2 + s) * 512 + k0;
#pragma unroll
                for (int j = 0; j < 8; ++j) o[j] = f2bf(wp[j]);
            }
        }
        *(short8*)(Wp1a + (size_t)t * 8) = o;
    } else if (t < 36864 + 3072) {
        int u = t - 36864;
        int l = u & 63;
        int kc = u >> 6;                 // ks*3+ct
        int ct2 = kc % 3, ks = kc / 3;
        int col = ct2 * 16 + (l & 15);
        short8 o;
#pragma unroll
        for (int j = 0; j < 8; ++j) {
            int kp = ks * 32 + (l >> 4) * 8 + j;      // permuted K slot (= c')
            int head = kp >> 6, fp = kp & 63;
            int l15 = fp >> 2, ctp = fp & 3;
            int ct = ((head & 1) << 2) | ctp;
            int gg = head >> 1;
            int orig_k = gg * 128 + ct * 16 + l15;
            o[j] = (col < NCLASS) ? f2bf(W2[(size_t)orig_k * NCLASS + col]) : (short)0;
        }
        *(short8*)(Wp2 + (size_t)u * 8) = o;
    }
}

// ---------------- gemm1: 3 rowtiles/block, scores as 9th B-tile, single dispatch ----
__global__ __launch_bounds__(256, 3) void gemm1(const float* __restrict__ x,
                                                const short* __restrict__ Wp1a,
                                                short* __restrict__ h1p,
                                                float* __restrict__ s1s,
                                                float* __restrict__ s1d) {
    __shared__ short As[RT_BLK * 16 * 64 * 8];     // 48 KB
    int w = threadIdx.x >> 6, l = threadIdx.x & 63;
    int g = w;                                 // wave = colgroup
    int rt0 = blockIdx.x * RT_BLK;
    int row0 = rt0 * 16;

    // stage 48 rows x 512 cols of x into LDS A-frag layout (swizzled slots)
#pragma unroll
    for (int u = 0; u < 4 * RT_BLK; ++u) {
        int idx = threadIdx.x + u * 256;       // 0..3071
        int rl = idx >> 6, cg = idx & 63;      // row-local (0..47), col-group
        int row = row0 + rl;
        short8 o;
        if (row < N_NODES) {
            const float* p = x + (size_t)row * NFEAT + cg * 8;
            f32x4 v0 = __builtin_nontemporal_load((const f32x4*)p);
            f32x4 v1 = __builtin_nontemporal_load((const f32x4*)(p + 4));
            o[0] = f2bf(v0[0]); o[1] = f2bf(v0[1]); o[2] = f2bf(v0[2]); o[3] = f2bf(v0[3]);
            o[4] = f2bf(v1[0]); o[5] = f2bf(v1[1]); o[6] = f2bf(v1[2]); o[7] = f2bf(v1[3]);
        } else {
#pragma unroll
            for (int j = 0; j < 8; ++j) o[j] = 0;
        }
        int rtl = rl >> 4, rloc = rl & 15, ks = cg >> 2, sub = cg & 3;
        int slot = (rtl * 16 + ks) * 64 + rloc + sub * 16;
        *(short8*)(As + swz(slot) * 8) = o;
    }
    __syncthreads();

    f32x4 acc[RT_BLK][9];
#pragma unroll
    for (int i = 0; i < RT_BLK; ++i)
#pragma unroll
        for (int ct = 0; ct < 9; ++ct) acc[i][ct] = (f32x4){0.f, 0.f, 0.f, 0.f};

    const short* bP = Wp1a + (size_t)g * (16 * 9 * 512) + l * 8;   // ks stride 4608
#pragma unroll 2
    for (int ks = 0; ks < 16; ++ks) {
        short8 b[9];
#pragma unroll
        for (int ct = 0; ct < 9; ++ct) b[ct] = *(const short8*)(bP + ks * 4608 + ct * 512);
        short8 a[RT_BLK];
#pragma unroll
        for (int i = 0; i < RT_BLK; ++i)
            a[i] = *(const short8*)(As + swz((i * 16 + ks) * 64 + l) * 8);
#pragma unroll
        for (int i = 0; i < RT_BLK; ++i)
#pragma unroll
            for (int ct = 0; ct < 9; ++ct)
                acc[i][ct] = __builtin_amdgcn_mfma_f32_16x16x32_bf16(a[i], b[ct], acc[i][ct], 0, 0, 0);
    }

    int l15 = l & 15;
    int rbase = (l >> 4) * 4;
#pragma unroll
    for (int i = 0; i < RT_BLK; ++i)
#pragma unroll
        for (int r = 0; r < 4; ++r) {
            int row = (rt0 + i) * 16 + rbase + r;
            if (row < N_NODES) {
                short4v o0, o1;
#pragma unroll
                for (int c = 0; c < 4; ++c) { o0[c] = f2bf(acc[i][c][r]); o1[c] = f2bf(acc[i][4 + c][r]); }
                size_t base = (size_t)row * 512 + g * 128 + l15 * 4;
                *(short4v*)(h1p + base) = o0;
                *(short4v*)(h1p + base + 64) = o1;
                float sv = acc[i][8][r];
                if (l15 == 0)      s1s[row * 8 + 2 * g]     = sv;
                else if (l15 == 1) s1d[row * 8 + 2 * g]     = sv;
                else if (l15 == 2) s1s[row * 8 + 2 * g + 1] = sv;
                else if (l15 == 3) s1d[row * 8 + 2 * g + 1] = sv;
            }
        }
}

// ---------------- fused layer-1 attention: wave per dst, ALL heads, single dispatch ----
__global__ __launch_bounds__(256, 4) void att1(const int* __restrict__ ptr,
                                               const int* __restrict__ esrc,
                                               const float* __restrict__ s1s,
                                               const float* __restrict__ s1d,
                                               const short* __restrict__ h1p,
                                               const float* __restrict__ b1,
                                               short* __restrict__ hcat) {
    int n = blockIdx.x * 4 + (threadIdx.x >> 6);
    int l = threadIdx.x & 63;
    if (n >= N_NODES) return;
    int beg = ptr[n], end = ptr[n + 1];
    int h = l >> 3;
    float sd = s1d[n * 8 + h];
    float den = 0.f;
    float acc[8] = {0.f, 0.f, 0.f, 0.f, 0.f, 0.f, 0.f, 0.f};
    const short* hb = h1p + l * 8;
    if (beg < end) {
        int last = end - 1;
        int p1 = (beg + 1 <= last) ? beg + 1 : last;
        int p2 = (beg + 2 <= last) ? beg + 2 : last;
        int p3 = (beg + 3 <= last) ? beg + 3 : last;
        int s0 = esrc[beg], s1 = esrc[p1], s2 = esrc[p2], s3 = esrc[p3];
        short8 v0 = *(const short8*)(hb + (size_t)s0 * 512);
        short8 v1 = *(const short8*)(hb + (size_t)s1 * 512);
        short8 v2 = *(const short8*)(hb + (size_t)s2 * 512);
        short8 v3 = *(const short8*)(hb + (size_t)s3 * 512);
        float ss0 = s1s[s0 * 8 + h], ss1 = s1s[s1 * 8 + h];
        float ss2 = s1s[s2 * 8 + h], ss3 = s1s[s3 * 8 + h];
        for (int i = beg; i < end; i += 4) {
            int ni = i + 4;
            int t0 = s0, t1 = s1, t2 = s2, t3 = s3;
            short8 u0 = v0, u1 = v1, u2 = v2, u3 = v3;
            float ts0 = ss0, ts1 = ss1, ts2 = ss2, ts3 = ss3;
            if (ni < end) {                       // wave-uniform branch
                int q1 = (ni + 1 <= last) ? ni + 1 : last;
                int q2 = (ni + 2 <= last) ? ni + 2 : last;
                int q3 = (ni + 3 <= last) ? ni + 3 : last;
                t0 = esrc[ni]; t1 = esrc[q1]; t2 = esrc[q2]; t3 = esrc[q3];
                u0 = *(const short8*)(hb + (size_t)t0 * 512);
                u1 = *(const short8*)(hb + (size_t)t1 * 512);
                u2 = *(const short8*)(hb + (size_t)t2 * 512);
                u3 = *(const short8*)(hb + (size_t)t3 * 512);
                ts0 = s1s[t0 * 8 + h]; ts1 = s1s[t1 * 8 + h];
                ts2 = s1s[t2 * 8 + h]; ts3 = s1s[t3 * 8 + h];
            }
            float e0 = ss0 + sd, e1 = ss1 + sd, e2 = ss2 + sd, e3 = ss3 + sd;
            e0 = fmaxf(e0, NEG_SLOPE * e0);
            e1 = fmaxf(e1, NEG_SLOPE * e1);
            e2 = fmaxf(e2, NEG_SLOPE * e2);
            e3 = fmaxf(e3, NEG_SLOPE * e3);
            float w0 = __expf(e0);
            float w1 = (i + 1 < end) ? __expf(e1) : 0.f;
            float w2 = (i + 2 < end) ? __expf(e2) : 0.f;
            float w3 = (i + 3 < end) ? __expf(e3) : 0.f;
            den += (w0 + w1) + (w2 + w3);
#pragma unroll
            for (int j = 0; j < 8; ++j)
                acc[j] += (w0 * bf2f(v0[j]) + w1 * bf2f(v1[j])) +
                          (w2 * bf2f(v2[j]) + w3 * bf2f(v3[j]));
            s0 = t0; s1 = t1; s2 = t2; s3 = t3;
            v0 = u0; v1 = u1; v2 = u2; v3 = u3;
            ss0 = ts0; ss1 = ts1; ss2 = ts2; ss3 = ts3;
        }
    }
    float rden = 1.f / fmaxf(den, 1e-16f);
    short8 o;
#pragma unroll
    for (int j = 0; j < 8; ++j) {
        // permuted slot c' = l*8+j  ->  orig b1 index = head*64 + (j&3)*16 + (l&7)*2 + (j>>2)
        int forig = (j & 3) * 16 + (l & 7) * 2 + (j >> 2);
        float v = acc[j] * rden + b1[h * 64 + forig];
        v = v > 0.f ? v : (__expf(v) - 1.f);    // ELU
        o[j] = f2bf(v);
    }
    *(short8*)(hcat + (size_t)n * 512 + l * 8) = o;
}

// ---------------- gemm2: row-major hcat A-frags + fused s2 scores; h2 PADDED to 64 cols ----
__global__ __launch_bounds__(256) void gemm2(const short* __restrict__ hcat,
                                             const short* __restrict__ Wp2,
                                             const float* __restrict__ a2,
                                             short* __restrict__ h2p,
                                             float* __restrict__ s2s,
                                             float* __restrict__ s2d) {
    int w = threadIdx.x >> 6, l = threadIdx.x & 63;
    int rt = blockIdx.x * 4 + w;                  // < 3128
    int arow = rt * 16 + (l & 15);
    const short* aBase = hcat + (size_t)arow * 512 + (l >> 4) * 8;
    f32x4 acc[3];
#pragma unroll
    for (int ct = 0; ct < 3; ++ct) acc[ct] = (f32x4){0.f, 0.f, 0.f, 0.f};
#pragma unroll 2
    for (int ks = 0; ks < 16; ++ks) {
        short8 a = *(const short8*)(aBase + ks * 32);
        const short* bp = Wp2 + (size_t)(ks * 3) * 512 + l * 8;
#pragma unroll
        for (int ct = 0; ct < 3; ++ct) {
            short8 b = *(const short8*)(bp + ct * 512);
            acc[ct] = __builtin_amdgcn_mfma_f32_16x16x32_bf16(a, b, acc[ct], 0, 0, 0);
        }
    }
    float ps[4] = {0.f, 0.f, 0.f, 0.f}, pd[4] = {0.f, 0.f, 0.f, 0.f};
    int cl = l & 15, rb = (l >> 4) * 4;
#pragma unroll
    for (int ct = 0; ct < 3; ++ct) {
        int col = ct * 16 + cl;
#pragma unroll
        for (int r = 0; r < 4; ++r) {
            int row = rt * 16 + rb + r;
            if (row < N_NODES) h2p[(size_t)row * 64 + col] = f2bf(acc[ct][r]);
        }
        if (col < NCLASS) {
#pragma unroll
            for (int r = 0; r < 4; ++r) {
                ps[r] += acc[ct][r] * a2[col];
                pd[r] += acc[ct][r] * a2[NCLASS + col];
            }
        }
    }
#pragma unroll
    for (int mask = 1; mask < 16; mask <<= 1)
#pragma unroll
        for (int r = 0; r < 4; ++r) {
            ps[r] += __shfl_xor(ps[r], mask);
            pd[r] += __shfl_xor(pd[r], mask);
        }
    if (cl == 0) {
#pragma unroll
        for (int r = 0; r < 4; ++r) {
            int row = rt * 16 + rb + r;
            if (row < N_NODES) { s2s[row] = ps[r]; s2d[row] = pd[r]; }
        }
    }
}

// ---------------- fused layer-2 attention + log_softmax: 4 edge-groups x 16 lanes ----
__global__ __launch_bounds__(256, 4) void att2(const int* __restrict__ ptr,
                                               const int* __restrict__ esrc,
                                               const float* __restrict__ s2s,
                                               const float* __restrict__ s2d,
                                               const short* __restrict__ h2p,
                                               const float* __restrict__ b2,
                                               float* __restrict__ out) {
    int n = blockIdx.x * 4 + (threadIdx.x >> 6);
    int l = threadIdx.x & 63;
    if (n >= N_NODES) return;
    int beg = ptr[n], end = ptr[n + 1];
    float sd = s2d[n];
    int grp = l >> 4, cl = l & 15;
    bool act16 = cl < 10;                 // classes cl*4..cl*4+3 valid iff cl<10
    float den = 0.f, a0 = 0.f, a1 = 0.f, a2v = 0.f, a3 = 0.f;
    if (beg < end) {
        int last = end - 1;
        for (int i = beg; i < end; i += 4) {
            int e = i + grp;
            bool valid = e < end;
            int src = esrc[valid ? e : last];
            float sc = s2s[src] + sd;
            sc = fmaxf(sc, NEG_SLOPE * sc);
            float wgt = valid ? __expf(sc) : 0.f;
            short4v hv = *(const short4v*)(h2p + (size_t)src * 64 + cl * 4);
            den += wgt;
            if (act16) {
                a0 += wgt * bf2f(hv[0]);
                a1 += wgt * bf2f(hv[1]);
                a2v += wgt * bf2f(hv[2]);
                a3 += wgt * bf2f(hv[3]);
            }
        }
    }
    // sum the 4 edge-groups (lanes with equal cl): xor 16, 32
#pragma unroll
    for (int m = 16; m < 64; m <<= 1) {
        den += __shfl_xor(den, m);
        a0  += __shfl_xor(a0, m);
        a1  += __shfl_xor(a1, m);
        a2v += __shfl_xor(a2v, m);
        a3  += __shfl_xor(a3, m);
    }
    float rden = 1.f / fmaxf(den, 1e-16f);
    float v0, v1, v2, v3;
    if (act16) {
        int c0 = cl * 4;
        v0 = a0 * rden + b2[c0 + 0];
        v1 = a1 * rden + b2[c0 + 1];
        v2 = a2v * rden + b2[c0 + 2];
        v3 = a3 * rden + b2[c0 + 3];
    } else { v0 = v1 = v2 = v3 = -INFINITY; }
    // log_softmax over 40 classes: reduce within each 16-lane quarter (quarters identical)
    float mx = fmaxf(fmaxf(v0, v1), fmaxf(v2, v3));
#pragma unroll
    for (int m = 1; m < 16; m <<= 1) mx = fmaxf(mx, __shfl_xor(mx, m));
    float e0 = act16 ? __expf(v0 - mx) : 0.f;
    float e1 = act16 ? __expf(v1 - mx) : 0.f;
    float e2 = act16 ? __expf(v2 - mx) : 0.f;
    float e3 = act16 ? __expf(v3 - mx) : 0.f;
    float s = (e0 + e1) + (e2 + e3);
#pragma unroll
    for (int m = 1; m < 16; m <<= 1) s += __shfl_xor(s, m);
    float ls = __logf(s);
    if (l < 16 && act16) {
        int c0 = cl * 4;
        out[(size_t)n * NCLASS + c0 + 0] = v0 - mx - ls;
        out[(size_t)n * NCLASS + c0 + 1] = v1 - mx - ls;
        out[(size_t)n * NCLASS + c0 + 2] = v2 - mx - ls;
        out[(size_t)n * NCLASS + c0 + 3] = v3 - mx - ls;
    }
}

// ---------------- launch ----------------

extern "C" void kernel_launch(void* const* d_in, const int* in_sizes, int n_in,
                              void* d_out, int out_size, void* d_ws, size_t ws_size,
                              hipStream_t stream) {
    const float* x  = (const float*)d_in[0];
    const int*   el = (const int*)d_in[1];
    const float* W1 = (const float*)d_in[2];
    const float* a1 = (const float*)d_in[3];
    const float* b1 = (const float*)d_in[4];
    const float* W2 = (const float*)d_in[5];
    const float* a2 = (const float*)d_in[6];
    const float* b2 = (const float*)d_in[7];
    float* out = (float*)d_out;

    short* sbase = (short*)d_ws;
    short* Wp1a  = sbase;                          //    294,912
    short* h2p   = sbase + 4000000;                //  3,200,000 (padded h2: 50000 x 64)
    short* hcat  = sbase + 25624576;               // 25,624,576 (row-major, permuted cols)
    short* h1p   = sbase + 51249152;               // 25,600,000
    short* Wp2   = sbase + 77111296;               //     24,576
    float* fbase = (float*)(sbase + 79135872);
    float* s1s   = fbase;                          //    400,000
    float* s1d   = fbase + 400000;                 //    400,000
    float* s2s   = fbase + 800000;                 //     50,000
    float* s2d   = fbase + 850000;                 //     50,000
    int*   ibase = (int*)(fbase + 900000);
    int*   deg    = ibase;                         //     50,000
    int*   ptr    = ibase + 50000;                 //     50,001
    int*   cursor = ibase + 100001;                //     50,000
    int*   esrc   = ibase + 150001;                //    800,000
    int*   loc    = ibase + 950001;                //     50,000
    int*   bsum   = ibase + 1000001;               //         64
    float* Waf    = (float*)(ibase + 1000128);     //      8,192 (Wa = W1@a1, fp32)

    // ---- CSR build ----
    hipMemsetAsync(deg, 0, (size_t)N_NODES * 4, stream);
    count_deg<<<(N_EDGES + 255) / 256, 256, 0, stream>>>(el, deg);
    scan1<<<SCAN_NBLK, 256, 0, stream>>>(deg, loc, bsum);
    scan3<<<SCAN_NBLK, 256, 0, stream>>>(deg, loc, bsum, ptr, cursor);
    scatter_k<<<(N_EDGES + 255) / 256, 256, 0, stream>>>(el, cursor, esrc);

    // ---- weight packing (Wa parallel, then fragment pack) ----
    pack_wa<<<512, 256, 0, stream>>>(W1, a1, Waf);
    pack_w<<<156, 256, 0, stream>>>(W1, W2, Waf, Wp1a, Wp2);

    // ---- layer 1 ----
    gemm1<<<GEMM1_GRID, 256, 0, stream>>>(x, Wp1a, h1p, s1s, s1d);
    att1<<<(N_NODES + 3) / 4, 256, 0, stream>>>(ptr, esrc, s1s, s1d, h1p, b1, hcat);

    // ---- layer 2 ----
    gemm2<<<782, 256, 0, stream>>>(hcat, Wp2, a2, h2p, s2s, s2d);
    att2<<<(N_NODES + 3) / 4, 256, 0, stream>>>(ptr, esrc, s2s, s2d, h2p, b2, out);
}

// Round 16
// 445.459 us; speedup vs baseline: 1.1317x; 1.0589x over previous
//
// GAT fused pipeline v3.7 — att2: 8 edge-groups x 8 lanes (8 load chains, short8
// gathers); scatter_k atomic-free via rank recorded in count_deg. Rest frozen v3.6.
#include <hip/hip_runtime.h>
#include <math.h>

#define N_NODES 50000
#define N_EDGES 800000
#define NFEAT 512
#define NHID 64
#define NHEAD 8
#define NCLASS 40
#define NEG_SLOPE 0.2f

#define N_RT 3125           // 50000/16 row tiles
#define SCAN_NBLK 49        // ceil(50000/1024)
#define RT_BLK 3            // rowtiles per gemm1 block (48 rows, 48KB LDS)
#define GEMM1_GRID 1042     // ceil(3125/3)

typedef __attribute__((ext_vector_type(8))) short short8;
typedef __attribute__((ext_vector_type(4))) short short4v;
typedef __attribute__((ext_vector_type(4))) float f32x4;

__device__ __forceinline__ float bf2f(short s) {
    return __uint_as_float(((unsigned)(unsigned short)s) << 16);
}
__device__ __forceinline__ short f2bf(float f) {
    unsigned u = __float_as_uint(f);
    unsigned r = (u + 0x7FFFu + ((u >> 16) & 1u)) >> 16;
    return (short)(unsigned short)r;
}
// LDS 16B-slot swizzle: staging writes 32-way -> conflict-free (verified r7:
// SQ_LDS_BANK_CONFLICT 2.8M -> 0); reads stay conflict-free; bijective.
__device__ __forceinline__ int swz(int s) { return s ^ ((s >> 4) & 7); }

// h1 row permutation: slot c' = head*64 + f'; orig feature: forig = ((f'&3)<<4)|(f'>>2).
// Wp1a layout (augmented): ((g*16+ks)*9 + ct)*64*8 shorts; ct=8 holds score
// columns [ss_h(2g), sd_h(2g), ss_h(2g+1), sd_h(2g+1), 0...] from Waf (pack_wa).

// ---------------- CSR build ----------------

// count_deg also records each edge's arrival rank (atomicAdd return) so
// scatter_k needs no atomics.
__global__ void count_deg(const int* __restrict__ el, int* __restrict__ deg,
                          int* __restrict__ rank) {
    int e = blockIdx.x * blockDim.x + threadIdx.x;
    if (e < N_EDGES) rank[e] = atomicAdd(&deg[el[N_EDGES + e]], 1);
}

__global__ __launch_bounds__(256) void scan1(const int* __restrict__ deg,
                                             int* __restrict__ loc,
                                             int* __restrict__ bsum) {
    int tid = threadIdx.x, lane = tid & 63, w = tid >> 6;
    int base = blockIdx.x * 1024 + tid * 4;
    int d0 = (base + 0 < N_NODES) ? deg[base + 0] : 0;
    int d1 = (base + 1 < N_NODES) ? deg[base + 1] : 0;
    int d2 = (base + 2 < N_NODES) ? deg[base + 2] : 0;
    int d3 = (base + 3 < N_NODES) ? deg[base + 3] : 0;
    int s0 = d0, s1 = s0 + d1, s2 = s1 + d2, s3 = s2 + d3;
    int t = s3;
#pragma unroll
    for (int d = 1; d < 64; d <<= 1) {
        int u = __shfl_up(t, d);
        if (lane >= d) t += u;
    }
    __shared__ int wsum[4];
    if (lane == 63) wsum[w] = t;
    __syncthreads();
    int woff = 0;
#pragma unroll
    for (int j = 0; j < 4; ++j) woff += (j < w) ? wsum[j] : 0;
    int excl = woff + t - s3;
    if (base + 0 < N_NODES) loc[base + 0] = excl + s0;
    if (base + 1 < N_NODES) loc[base + 1] = excl + s1;
    if (base + 2 < N_NODES) loc[base + 2] = excl + s2;
    if (base + 3 < N_NODES) loc[base + 3] = excl + s3;
    if (tid == 255) bsum[blockIdx.x] = woff + t;
}

// scan3: ptr only (cursor no longer needed — scatter is rank-based)
__global__ __launch_bounds__(256) void scan3(const int* __restrict__ loc,
                                             const int* __restrict__ bsum,
                                             int* __restrict__ ptr) {
    __shared__ int sOff;
    if (threadIdx.x < 64) {
        int lane = threadIdx.x;
        int v = (lane < SCAN_NBLK && lane < (int)blockIdx.x) ? bsum[lane] : 0;
#pragma unroll
        for (int m = 1; m < 64; m <<= 1) v += __shfl_xor(v, m);
        if (lane == 0) sOff = v;
    }
    __syncthreads();
    int off = sOff;
    int base = blockIdx.x * 1024 + threadIdx.x * 4;
    if (blockIdx.x == 0 && threadIdx.x == 0) ptr[0] = 0;
#pragma unroll
    for (int k = 0; k < 4; ++k) {
        int i = base + k;
        if (i < N_NODES) ptr[i + 1] = off + loc[i];
    }
}

// atomic-free scatter: position = ptr[dst] + rank[e]
__global__ void scatter_k(const int* __restrict__ el, const int* __restrict__ ptr,
                          const int* __restrict__ rank, int* __restrict__ esrc) {
    int e = blockIdx.x * blockDim.x + threadIdx.x;
    if (e >= N_EDGES) return;
    int dst = el[N_EDGES + e];
    esrc[ptr[dst] + rank[e]] = el[e];
}

// ---------------- pack_wa: Waf[(head*2+s)*512 + k] = sum_f W1[head][k][f]*a1[head][s*64+f] ----
__global__ __launch_bounds__(256) void pack_wa(const float* __restrict__ W1,
                                               const float* __restrict__ a1,
                                               float* __restrict__ Waf) {
    int q = blockIdx.x * 16 + (threadIdx.x >> 4);   // output id, [0, 8192)
    int r = threadIdx.x & 15;
    int k = q & 511;
    int hs = q >> 9;                                // head*2+s
    int head = hs >> 1, s = hs & 1;
    f32x4 wv = *(const f32x4*)(W1 + (size_t)head * NFEAT * NHID + (size_t)k * NHID + r * 4);
    f32x4 av = *(const f32x4*)(a1 + head * 128 + s * 64 + r * 4);
    float sum = wv[0] * av[0] + wv[1] * av[1] + wv[2] * av[2] + wv[3] * av[3];
#pragma unroll
    for (int m = 1; m < 16; m <<= 1) sum += __shfl_xor(sum, m);
    if (r == 0) Waf[q] = sum;
}

// ---------------- pack W1(+scores), W2 into MFMA B-fragment layout (bf16) ----------------
__global__ __launch_bounds__(256) void pack_w(const float* __restrict__ W1,
                                              const float* __restrict__ W2,
                                              const float* __restrict__ Waf,
                                              short* __restrict__ Wp1a,
                                              short* __restrict__ Wp2) {
    int t = blockIdx.x * 256 + threadIdx.x;
    if (t < 36864) {                    // 4g x 16ks x 9ct x 64l
        int l = t & 63;
        int idx = t >> 6;               // 0..575
        int ct = idx % 9;
        int ksg = idx / 9;              // g*16+ks
        int ks = ksg & 15, g = ksg >> 4;
        short8 o;
        if (ct < 8) {
            int c = g * 128 + ct * 16 + (l & 15);
            int head = c >> 6, f = c & 63;
            int k0 = ks * 32 + (l >> 4) * 8;
#pragma unroll
            for (int j = 0; j < 8; ++j)
                o[j] = f2bf(W1[(size_t)head * NFEAT * NHID + (k0 + j) * NHID + f]);
        } else {
            // score columns: col 0..3 = [ss(2g), sd(2g), ss(2g+1), sd(2g+1)] from Waf
            int col = l & 15;
            int k0 = ks * 32 + (l >> 4) * 8;
#pragma unroll
            for (int j = 0; j < 8; ++j) o[j] = 0;
            if (col < 4) {
                int head = 2 * g + (col >> 1);
                int s = col & 1;
                const float* wp = Waf + (head * 2 + s) * 512 + k0;
#pragma unroll
                for (int j = 0; j < 8; ++j) o[j] = f2bf(wp[j]);
            }
        }
        *(short8*)(Wp1a + (size_t)t * 8) = o;
    } else if (t < 36864 + 3072) {
        int u = t - 36864;
        int l = u & 63;
        int kc = u >> 6;                 // ks*3+ct
        int ct2 = kc % 3, ks = kc / 3;
        int col = ct2 * 16 + (l & 15);
        short8 o;
#pragma unroll
        for (int j = 0; j < 8; ++j) {
            int kp = ks * 32 + (l >> 4) * 8 + j;      // permuted K slot (= c')
            int head = kp >> 6, fp = kp & 63;
            int l15 = fp >> 2, ctp = fp & 3;
            int ct = ((head & 1) << 2) | ctp;
            int gg = head >> 1;
            int orig_k = gg * 128 + ct * 16 + l15;
            o[j] = (col < NCLASS) ? f2bf(W2[(size_t)orig_k * NCLASS + col]) : (short)0;
        }
        *(short8*)(Wp2 + (size_t)u * 8) = o;
    }
}

// ---------------- gemm1: 3 rowtiles/block, scores as 9th B-tile ----
__global__ __launch_bounds__(256, 3) void gemm1(const float* __restrict__ x,
                                                const short* __restrict__ Wp1a,
                                                short* __restrict__ h1p,
                                                float* __restrict__ s1s,
                                                float* __restrict__ s1d) {
    __shared__ short As[RT_BLK * 16 * 64 * 8];     // 48 KB
    int w = threadIdx.x >> 6, l = threadIdx.x & 63;
    int g = w;                                 // wave = colgroup
    int rt0 = blockIdx.x * RT_BLK;
    int row0 = rt0 * 16;

#pragma unroll
    for (int u = 0; u < 4 * RT_BLK; ++u) {
        int idx = threadIdx.x + u * 256;       // 0..3071
        int rl = idx >> 6, cg = idx & 63;      // row-local (0..47), col-group
        int row = row0 + rl;
        short8 o;
        if (row < N_NODES) {
            const float* p = x + (size_t)row * NFEAT + cg * 8;
            f32x4 v0 = __builtin_nontemporal_load((const f32x4*)p);
            f32x4 v1 = __builtin_nontemporal_load((const f32x4*)(p + 4));
            o[0] = f2bf(v0[0]); o[1] = f2bf(v0[1]); o[2] = f2bf(v0[2]); o[3] = f2bf(v0[3]);
            o[4] = f2bf(v1[0]); o[5] = f2bf(v1[1]); o[6] = f2bf(v1[2]); o[7] = f2bf(v1[3]);
        } else {
#pragma unroll
            for (int j = 0; j < 8; ++j) o[j] = 0;
        }
        int rtl = rl >> 4, rloc = rl & 15, ks = cg >> 2, sub = cg & 3;
        int slot = (rtl * 16 + ks) * 64 + rloc + sub * 16;
        *(short8*)(As + swz(slot) * 8) = o;
    }
    __syncthreads();

    f32x4 acc[RT_BLK][9];
#pragma unroll
    for (int i = 0; i < RT_BLK; ++i)
#pragma unroll
        for (int ct = 0; ct < 9; ++ct) acc[i][ct] = (f32x4){0.f, 0.f, 0.f, 0.f};

    const short* bP = Wp1a + (size_t)g * (16 * 9 * 512) + l * 8;   // ks stride 4608
#pragma unroll 2
    for (int ks = 0; ks < 16; ++ks) {
        short8 b[9];
#pragma unroll
        for (int ct = 0; ct < 9; ++ct) b[ct] = *(const short8*)(bP + ks * 4608 + ct * 512);
        short8 a[RT_BLK];
#pragma unroll
        for (int i = 0; i < RT_BLK; ++i)
            a[i] = *(const short8*)(As + swz((i * 16 + ks) * 64 + l) * 8);
#pragma unroll
        for (int i = 0; i < RT_BLK; ++i)
#pragma unroll
            for (int ct = 0; ct < 9; ++ct)
                acc[i][ct] = __builtin_amdgcn_mfma_f32_16x16x32_bf16(a[i], b[ct], acc[i][ct], 0, 0, 0);
    }

    int l15 = l & 15;
    int rbase = (l >> 4) * 4;
#pragma unroll
    for (int i = 0; i < RT_BLK; ++i)
#pragma unroll
        for (int r = 0; r < 4; ++r) {
            int row = (rt0 + i) * 16 + rbase + r;
            if (row < N_NODES) {
                short4v o0, o1;
#pragma unroll
                for (int c = 0; c < 4; ++c) { o0[c] = f2bf(acc[i][c][r]); o1[c] = f2bf(acc[i][4 + c][r]); }
                size_t base = (size_t)row * 512 + g * 128 + l15 * 4;
                *(short4v*)(h1p + base) = o0;
                *(short4v*)(h1p + base + 64) = o1;
                float sv = acc[i][8][r];
                if (l15 == 0)      s1s[row * 8 + 2 * g]     = sv;
                else if (l15 == 1) s1d[row * 8 + 2 * g]     = sv;
                else if (l15 == 2) s1s[row * 8 + 2 * g + 1] = sv;
                else if (l15 == 3) s1d[row * 8 + 2 * g + 1] = sv;
            }
        }
}

// ---------------- fused layer-1 attention: wave per dst, ALL heads ----
__global__ __launch_bounds__(256, 4) void att1(const int* __restrict__ ptr,
                                               const int* __restrict__ esrc,
                                               const float* __restrict__ s1s,
                                               const float* __restrict__ s1d,
                                               const short* __restrict__ h1p,
                                               const float* __restrict__ b1,
                                               short* __restrict__ hcat) {
    int n = blockIdx.x * 4 + (threadIdx.x >> 6);
    int l = threadIdx.x & 63;
    if (n >= N_NODES) return;
    int beg = ptr[n], end = ptr[n + 1];
    int h = l >> 3;
    float sd = s1d[n * 8 + h];
    float den = 0.f;
    float acc[8] = {0.f, 0.f, 0.f, 0.f, 0.f, 0.f, 0.f, 0.f};
    const short* hb = h1p + l * 8;
    if (beg < end) {
        int last = end - 1;
        int p1 = (beg + 1 <= last) ? beg + 1 : last;
        int p2 = (beg + 2 <= last) ? beg + 2 : last;
        int p3 = (beg + 3 <= last) ? beg + 3 : last;
        int s0 = esrc[beg], s1 = esrc[p1], s2 = esrc[p2], s3 = esrc[p3];
        short8 v0 = *(const short8*)(hb + (size_t)s0 * 512);
        short8 v1 = *(const short8*)(hb + (size_t)s1 * 512);
        short8 v2 = *(const short8*)(hb + (size_t)s2 * 512);
        short8 v3 = *(const short8*)(hb + (size_t)s3 * 512);
        float ss0 = s1s[s0 * 8 + h], ss1 = s1s[s1 * 8 + h];
        float ss2 = s1s[s2 * 8 + h], ss3 = s1s[s3 * 8 + h];
        for (int i = beg; i < end; i += 4) {
            int ni = i + 4;
            int t0 = s0, t1 = s1, t2 = s2, t3 = s3;
            short8 u0 = v0, u1 = v1, u2 = v2, u3 = v3;
            float ts0 = ss0, ts1 = ss1, ts2 = ss2, ts3 = ss3;
            if (ni < end) {                       // wave-uniform branch
                int q1 = (ni + 1 <= last) ? ni + 1 : last;
                int q2 = (ni + 2 <= last) ? ni + 2 : last;
                int q3 = (ni + 3 <= last) ? ni + 3 : last;
                t0 = esrc[ni]; t1 = esrc[q1]; t2 = esrc[q2]; t3 = esrc[q3];
                u0 = *(const short8*)(hb + (size_t)t0 * 512);
                u1 = *(const short8*)(hb + (size_t)t1 * 512);
                u2 = *(const short8*)(hb + (size_t)t2 * 512);
                u3 = *(const short8*)(hb + (size_t)t3 * 512);
                ts0 = s1s[t0 * 8 + h]; ts1 = s1s[t1 * 8 + h];
                ts2 = s1s[t2 * 8 + h]; ts3 = s1s[t3 * 8 + h];
            }
            float e0 = ss0 + sd, e1 = ss1 + sd, e2 = ss2 + sd, e3 = ss3 + sd;
            e0 = fmaxf(e0, NEG_SLOPE * e0);
            e1 = fmaxf(e1, NEG_SLOPE * e1);
            e2 = fmaxf(e2, NEG_SLOPE * e2);
            e3 = fmaxf(e3, NEG_SLOPE * e3);
            float w0 = __expf(e0);
            float w1 = (i + 1 < end) ? __expf(e1) : 0.f;
            float w2 = (i + 2 < end) ? __expf(e2) : 0.f;
            float w3 = (i + 3 < end) ? __expf(e3) : 0.f;
            den += (w0 + w1) + (w2 + w3);
#pragma unroll
            for (int j = 0; j < 8; ++j)
                acc[j] += (w0 * bf2f(v0[j]) + w1 * bf2f(v1[j])) +
                          (w2 * bf2f(v2[j]) + w3 * bf2f(v3[j]));
            s0 = t0; s1 = t1; s2 = t2; s3 = t3;
            v0 = u0; v1 = u1; v2 = u2; v3 = u3;
            ss0 = ts0; ss1 = ts1; ss2 = ts2; ss3 = ts3;
        }
    }
    float rden = 1.f / fmaxf(den, 1e-16f);
    short8 o;
#pragma unroll
    for (int j = 0; j < 8; ++j) {
        // permuted slot c' = l*8+j  ->  orig b1 index = head*64 + (j&3)*16 + (l&7)*2 + (j>>2)
        int forig = (j & 3) * 16 + (l & 7) * 2 + (j >> 2);
        float v = acc[j] * rden + b1[h * 64 + forig];
        v = v > 0.f ? v : (__expf(v) - 1.f);    // ELU
        o[j] = f2bf(v);
    }
    *(short8*)(hcat + (size_t)n * 512 + l * 8) = o;
}

// ---------------- gemm2: row-major hcat A-frags + fused s2 scores; h2 PADDED to 64 cols ----
__global__ __launch_bounds__(256) void gemm2(const short* __restrict__ hcat,
                                             const short* __restrict__ Wp2,
                                             const float* __restrict__ a2,
                                             short* __restrict__ h2p,
                                             float* __restrict__ s2s,
                                             float* __restrict__ s2d) {
    int w = threadIdx.x >> 6, l = threadIdx.x & 63;
    int rt = blockIdx.x * 4 + w;                  // < 3128
    int arow = rt * 16 + (l & 15);
    const short* aBase = hcat + (size_t)arow * 512 + (l >> 4) * 8;
    f32x4 acc[3];
#pragma unroll
    for (int ct = 0; ct < 3; ++ct) acc[ct] = (f32x4){0.f, 0.f, 0.f, 0.f};
#pragma unroll 2
    for (int ks = 0; ks < 16; ++ks) {
        short8 a = *(const short8*)(aBase + ks * 32);
        const short* bp = Wp2 + (size_t)(ks * 3) * 512 + l * 8;
#pragma unroll
        for (int ct = 0; ct < 3; ++ct) {
            short8 b = *(const short8*)(bp + ct * 512);
            acc[ct] = __builtin_amdgcn_mfma_f32_16x16x32_bf16(a, b, acc[ct], 0, 0, 0);
        }
    }
    float ps[4] = {0.f, 0.f, 0.f, 0.f}, pd[4] = {0.f, 0.f, 0.f, 0.f};
    int cl = l & 15, rb = (l >> 4) * 4;
#pragma unroll
    for (int ct = 0; ct < 3; ++ct) {
        int col = ct * 16 + cl;
#pragma unroll
        for (int r = 0; r < 4; ++r) {
            int row = rt * 16 + rb + r;
            if (row < N_NODES) h2p[(size_t)row * 64 + col] = f2bf(acc[ct][r]);
        }
        if (col < NCLASS) {
#pragma unroll
            for (int r = 0; r < 4; ++r) {
                ps[r] += acc[ct][r] * a2[col];
                pd[r] += acc[ct][r] * a2[NCLASS + col];
            }
        }
    }
#pragma unroll
    for (int mask = 1; mask < 16; mask <<= 1)
#pragma unroll
        for (int r = 0; r < 4; ++r) {
            ps[r] += __shfl_xor(ps[r], mask);
            pd[r] += __shfl_xor(pd[r], mask);
        }
    if (cl == 0) {
#pragma unroll
        for (int r = 0; r < 4; ++r) {
            int row = rt * 16 + rb + r;
            if (row < N_NODES) { s2s[row] = ps[r]; s2d[row] = pd[r]; }
        }
    }
}

// ---------------- fused layer-2 attention + log_softmax: 8 edge-groups x 8 lanes ----
// grp = l>>3 owns edge i+grp (8 independent load chains); cl = l&7 owns classes
// cl*8..cl*8+7 (short8 16B from h2p padded to 64). Group-reduce xor(8,16,32);
// log-softmax across the 8 cl-lanes xor(1,2,4). act iff cl<5 (5*8=40 classes).
__global__ __launch_bounds__(256, 4) void att2(const int* __restrict__ ptr,
                                               const int* __restrict__ esrc,
                                               const float* __restrict__ s2s,
                                               const float* __restrict__ s2d,
                                               const short* __restrict__ h2p,
                                               const float* __restrict__ b2,
                                               float* __restrict__ out) {
    int n = blockIdx.x * 4 + (threadIdx.x >> 6);
    int l = threadIdx.x & 63;
    if (n >= N_NODES) return;
    int beg = ptr[n], end = ptr[n + 1];
    float sd = s2d[n];
    int grp = l >> 3, cl = l & 7;
    bool act = cl < 5;                    // classes cl*8..cl*8+7 valid iff cl<5
    float den = 0.f;
    float a[8] = {0.f, 0.f, 0.f, 0.f, 0.f, 0.f, 0.f, 0.f};
    if (beg < end) {
        int last = end - 1;
        for (int i = beg; i < end; i += 8) {
            int e = i + grp;
            bool valid = e < end;
            int src = esrc[valid ? e : last];
            float sc = s2s[src] + sd;
            sc = fmaxf(sc, NEG_SLOPE * sc);
            float wgt = valid ? __expf(sc) : 0.f;
            short8 hv = *(const short8*)(h2p + (size_t)src * 64 + cl * 8);
            den += wgt;
            if (act) {
#pragma unroll
                for (int j = 0; j < 8; ++j) a[j] += wgt * bf2f(hv[j]);
            }
        }
    }
    // sum the 8 edge-groups (lanes with equal cl): xor 8, 16, 32
#pragma unroll
    for (int m = 8; m < 64; m <<= 1) {
        den += __shfl_xor(den, m);
#pragma unroll
        for (int j = 0; j < 8; ++j) a[j] += __shfl_xor(a[j], m);
    }
    float rden = 1.f / fmaxf(den, 1e-16f);
    float v[8];
    float mx = -INFINITY;
#pragma unroll
    for (int j = 0; j < 8; ++j) {
        v[j] = act ? (a[j] * rden + b2[cl * 8 + j]) : -INFINITY;
        mx = fmaxf(mx, v[j]);
    }
    // log_softmax across the 8 cl-lanes of this group: xor 1, 2, 4
#pragma unroll
    for (int m = 1; m < 8; m <<= 1) mx = fmaxf(mx, __shfl_xor(mx, m));
    float s = 0.f;
#pragma unroll
    for (int j = 0; j < 8; ++j) s += act ? __expf(v[j] - mx) : 0.f;
#pragma unroll
    for (int m = 1; m < 8; m <<= 1) s += __shfl_xor(s, m);
    float ls = __logf(s);
    if (l < 8 && act) {                   // group 0 writes, two float4 per lane
        float* op = out + (size_t)n * NCLASS + cl * 8;
        f32x4 o0 = {v[0] - mx - ls, v[1] - mx - ls, v[2] - mx - ls, v[3] - mx - ls};
        f32x4 o1 = {v[4] - mx - ls, v[5] - mx - ls, v[6] - mx - ls, v[7] - mx - ls};
        *(f32x4*)op = o0;
        *(f32x4*)(op + 4) = o1;
    }
}

// ---------------- launch ----------------

extern "C" void kernel_launch(void* const* d_in, const int* in_sizes, int n_in,
                              void* d_out, int out_size, void* d_ws, size_t ws_size,
                              hipStream_t stream) {
    const float* x  = (const float*)d_in[0];
    const int*   el = (const int*)d_in[1];
    const float* W1 = (const float*)d_in[2];
    const float* a1 = (const float*)d_in[3];
    const float* b1 = (const float*)d_in[4];
    const float* W2 = (const float*)d_in[5];
    const float* a2 = (const float*)d_in[6];
    const float* b2 = (const float*)d_in[7];
    float* out = (float*)d_out;

    short* sbase = (short*)d_ws;
    short* Wp1a  = sbase;                          //    294,912
    short* h2p   = sbase + 4000000;                //  3,200,000 (padded h2: 50000 x 64)
    short* hcat  = sbase + 25624576;               // 25,624,576 (row-major, permuted cols)
    short* h1p   = sbase + 51249152;               // 25,600,000
    short* Wp2   = sbase + 77111296;               //     24,576
    float* fbase = (float*)(sbase + 79135872);
    float* s1s   = fbase;                          //    400,000
    float* s1d   = fbase + 400000;                 //    400,000
    float* s2s   = fbase + 800000;                 //     50,000
    float* s2d   = fbase + 850000;                 //     50,000
    int*   ibase = (int*)(fbase + 900000);
    int*   deg    = ibase;                         //     50,000
    int*   ptr    = ibase + 50000;                 //     50,001
    int*   esrc   = ibase + 100001;                //    800,000
    int*   loc    = ibase + 900001;                //     50,000
    int*   bsum   = ibase + 950001;                //         64
    float* Waf    = (float*)(ibase + 950080);      //      8,192 (Wa = W1@a1, fp32)
    int*   rank   = ibase + 958272;                //    800,000 (edge arrival rank)

    // ---- CSR build (scatter is atomic-free via rank) ----
    hipMemsetAsync(deg, 0, (size_t)N_NODES * 4, stream);
    count_deg<<<(N_EDGES + 255) / 256, 256, 0, stream>>>(el, deg, rank);
    scan1<<<SCAN_NBLK, 256, 0, stream>>>(deg, loc, bsum);
    scan3<<<SCAN_NBLK, 256, 0, stream>>>(loc, bsum, ptr);
    scatter_k<<<(N_EDGES + 255) / 256, 256, 0, stream>>>(el, ptr, rank, esrc);

    // ---- weight packing (Wa parallel, then fragment pack) ----
    pack_wa<<<512, 256, 0, stream>>>(W1, a1, Waf);
    pack_w<<<156, 256, 0, stream>>>(W1, W2, Waf, Wp1a, Wp2);

    // ---- layer 1 ----
    gemm1<<<GEMM1_GRID, 256, 0, stream>>>(x, Wp1a, h1p, s1s, s1d);
    att1<<<(N_NODES + 3) / 4, 256, 0, stream>>>(ptr, esrc, s1s, s1d, h1p, b1, hcat);

    // ---- layer 2 ----
    gemm2<<<782, 256, 0, stream>>>(hcat, Wp2, a2, h2p, s2s, s2d);
    att2<<<(N_NODES + 3) / 4, 256, 0, stream>>>(ptr, esrc, s2s, s2d, h2p, b2, out);
}